// Round 11
// baseline (838.206 us; speedup 1.0000x reference)
//
#include <hip/hip_runtime.h>

#define H 128
#define LN_EPS 1e-5f

typedef __attribute__((ext_vector_type(8))) short bf16x8;
typedef __attribute__((ext_vector_type(4))) float f32x4;

__device__ __forceinline__ ushort f2bf(float f) {
    unsigned u = __builtin_bit_cast(unsigned, f);
    u += 0x7fffu + ((u >> 16) & 1u);          // RNE
    return (ushort)(u >> 16);
}

__device__ __forceinline__ float bf2f(ushort u) {
    return __builtin_bit_cast(float, (unsigned)u << 16);
}

// 2x fp32 -> packed bf16x2 (RNE), single instruction
__device__ __forceinline__ unsigned cvt_pk(float lo, float hi) {
    unsigned r;
    asm("v_cvt_pk_bf16_f32 %0, %1, %2" : "=v"(r) : "v"(lo), "v"(hi));
    return r;
}

__device__ __forceinline__ f32x4 mfma16(bf16x8 a, bf16x8 b, f32x4 c) {
    return __builtin_amdgcn_mfma_f32_16x16x32_bf16(a, b, c, 0, 0, 0);
}

// ---------------------------------------------------------------------------
// counting-sort by destination, then gather-sum (replaces atomic scatter)
// ---------------------------------------------------------------------------
__global__ __launch_bounds__(256) void hist_kernel(
    const int* __restrict__ ei, int* __restrict__ cnt, int E)
{
    int i = blockIdx.x * 256 + threadIdx.x;
    if (i < E) atomicAdd(&cnt[ei[E + i]], 1);
}

__global__ __launch_bounds__(1024) void scan_kernel(
    const int* __restrict__ cnt, int* __restrict__ off,
    int* __restrict__ cursor, int N)
{
    __shared__ int s[1024];
    const int t = threadIdx.x;
    const int chunk = (N + 1023) / 1024;
    const int lo = t * chunk, hi = min(lo + chunk, N);
    int sum = 0;
    for (int i = lo; i < hi; ++i) sum += cnt[i];
    s[t] = sum;
    __syncthreads();
    for (int d = 1; d < 1024; d <<= 1) {
        int v = (t >= d) ? s[t - d] : 0;
        __syncthreads();
        s[t] += v;
        __syncthreads();
    }
    int running = s[t] - sum;
    for (int i = lo; i < hi; ++i) {
        off[i] = running;
        cursor[i] = running;
        running += cnt[i];
    }
    if (t == 1023) off[N] = running;
}

__global__ __launch_bounds__(256) void reorder_kernel(
    const int* __restrict__ ei, int* __restrict__ cursor,
    int* __restrict__ sorted, int E)
{
    int i = blockIdx.x * 256 + threadIdx.x;
    if (i < E) {
        int pos = atomicAdd(&cursor[ei[E + i]], 1);
        sorted[pos] = i;
    }
}

// segsum + optional bf16-copy of e (each edge row touched exactly once here)
__global__ __launch_bounds__(256) void segsum_kernel(
    const float* __restrict__ e, const int* __restrict__ sorted,
    const int* __restrict__ off, float* __restrict__ msgs,
    ushort* __restrict__ ebf, int N)
{
    int node = blockIdx.x * 4 + (threadIdx.x >> 6);
    int lane = threadIdx.x & 63;
    if (node >= N) return;
    int beg = off[node], end = off[node + 1];
    float ax = 0.f, ay = 0.f;
    for (int base = beg; base < end; base += 64) {
        int eid_l = (base + lane < end) ? sorted[base + lane] : 0;
        int cnt = min(64, end - base);
        int i = 0;
        for (; i + 4 <= cnt; i += 4) {
            int e0 = __shfl(eid_l, i), e1 = __shfl(eid_l, i + 1);
            int e2 = __shfl(eid_l, i + 2), e3 = __shfl(eid_l, i + 3);
            float2 v0 = *reinterpret_cast<const float2*>(e + (size_t)e0 * H + lane * 2);
            float2 v1 = *reinterpret_cast<const float2*>(e + (size_t)e1 * H + lane * 2);
            float2 v2 = *reinterpret_cast<const float2*>(e + (size_t)e2 * H + lane * 2);
            float2 v3 = *reinterpret_cast<const float2*>(e + (size_t)e3 * H + lane * 2);
            if (ebf) {
                *reinterpret_cast<unsigned*>(ebf + (size_t)e0 * H + lane * 2) = cvt_pk(v0.x, v0.y);
                *reinterpret_cast<unsigned*>(ebf + (size_t)e1 * H + lane * 2) = cvt_pk(v1.x, v1.y);
                *reinterpret_cast<unsigned*>(ebf + (size_t)e2 * H + lane * 2) = cvt_pk(v2.x, v2.y);
                *reinterpret_cast<unsigned*>(ebf + (size_t)e3 * H + lane * 2) = cvt_pk(v3.x, v3.y);
            }
            ax += v0.x + v1.x + v2.x + v3.x;
            ay += v0.y + v1.y + v2.y + v3.y;
        }
        for (; i < cnt; ++i) {
            int eid = __shfl(eid_l, i);
            float2 v = *reinterpret_cast<const float2*>(e + (size_t)eid * H + lane * 2);
            if (ebf)
                *reinterpret_cast<unsigned*>(ebf + (size_t)eid * H + lane * 2) = cvt_pk(v.x, v.y);
            ax += v.x; ay += v.y;
        }
    }
    *reinterpret_cast<float2*>(msgs + (size_t)node * H + lane * 2) = make_float2(ax, ay);
}

// ---------------------------------------------------------------------------
// W[K][128] fp32 -> Wt[128][K] bf16
// ---------------------------------------------------------------------------
__global__ __launch_bounds__(256) void wtrans_kernel(
    const float* __restrict__ W, ushort* __restrict__ Wt, int K)
{
    int idx = blockIdx.x * 256 + threadIdx.x;
    if (idx >= K * H) return;
    int k = idx >> 7, n = idx & (H - 1);
    Wt[n * K + k] = f2bf(W[idx]);
}

// ---------------------------------------------------------------------------
// Node MLP (fused with Pa/Pb precompute):
//   [x|msgs](256) -> L1 -> LN -> SiLU -> L2 -> +x -> x_out
//   then Pa = xo@We1[0:128], Pb = xo@We1[128:256]
// ---------------------------------------------------------------------------
__global__ __launch_bounds__(256, 3) void node_mlp_kernel(
    const float* __restrict__ x, const float* __restrict__ msgs,
    const ushort* __restrict__ W1t, const float* __restrict__ b1,
    const float* __restrict__ g1, const float* __restrict__ be1,
    const ushort* __restrict__ W2t, const float* __restrict__ b2,
    const ushort* __restrict__ We1t,
    float* __restrict__ x_out,
    ushort* __restrict__ Pa, ushort* __restrict__ Pb, int N)
{
    __shared__ ushort smem[64 * 264];    // staging; h/xo [64][136] alias
    __shared__ float part_s[2][64], part_q[2][64];

    const int tid = threadIdx.x;
    const int row0 = blockIdx.x * 64;

    for (int idx = tid; idx < 64 * 64; idx += 256) {
        int r = idx >> 6, c4 = idx & 63;
        int row = row0 + r;
        float4 v = make_float4(0.f, 0.f, 0.f, 0.f);
        if (row < N)
            v = (c4 < 32) ? reinterpret_cast<const float4*>(x + (size_t)row * H)[c4]
                          : reinterpret_cast<const float4*>(msgs + (size_t)row * H)[c4 - 32];
        uint2 pk = make_uint2(cvt_pk(v.x, v.y), cvt_pk(v.z, v.w));
        *reinterpret_cast<uint2*>(&smem[r * 264 + c4 * 4]) = pk;
    }
    __syncthreads();

    const int lane = tid & 63, w = tid >> 6;
    const int l15 = lane & 15, lg = lane >> 4;
    const int mrow = (w & 1) * 32, ncol = (w >> 1) * 64;
    const int rA0 = mrow + l15, rA1 = mrow + 16 + l15;

    const ushort* pi0 = smem + (size_t)rA0 * 264;
    const ushort* pi1 = smem + (size_t)rA1 * 264;
    const ushort* pw1 = W1t + (size_t)(ncol + l15) * 256;

    f32x4 acc[2][4];
    #pragma unroll
    for (int mt = 0; mt < 2; ++mt)
        #pragma unroll
        for (int nt = 0; nt < 4; ++nt)
            acc[mt][nt] = (f32x4){0.f, 0.f, 0.f, 0.f};

    #pragma unroll
    for (int ks = 0; ks < 8; ++ks) {
        int k0 = ks * 32 + lg * 8;
        bf16x8 a0 = *reinterpret_cast<const bf16x8*>(pi0 + k0);
        bf16x8 a1 = *reinterpret_cast<const bf16x8*>(pi1 + k0);
        #pragma unroll
        for (int nt = 0; nt < 4; ++nt) {
            bf16x8 bfr = *reinterpret_cast<const bf16x8*>(pw1 + (size_t)nt * 16 * 256 + k0);
            acc[0][nt] = mfma16(a0, bfr, acc[0][nt]);
            acc[1][nt] = mfma16(a1, bfr, acc[1][nt]);
        }
    }

    float b1c[4], g1c[4], be1c[4];
    #pragma unroll
    for (int nt = 0; nt < 4; ++nt) {
        int c = ncol + nt * 16 + l15;
        b1c[nt] = b1[c]; g1c[nt] = g1[c]; be1c[nt] = be1[c];
    }
    #pragma unroll
    for (int mt = 0; mt < 2; ++mt)
        #pragma unroll
        for (int nt = 0; nt < 4; ++nt)
            #pragma unroll
            for (int r = 0; r < 4; ++r)
                acc[mt][nt][r] += b1c[nt];

    #pragma unroll
    for (int mt = 0; mt < 2; ++mt) {
        #pragma unroll
        for (int r = 0; r < 4; ++r) {
            float s = acc[mt][0][r] + acc[mt][1][r] + acc[mt][2][r] + acc[mt][3][r];
            float q = acc[mt][0][r] * acc[mt][0][r] + acc[mt][1][r] * acc[mt][1][r]
                    + acc[mt][2][r] * acc[mt][2][r] + acc[mt][3][r] * acc[mt][3][r];
            #pragma unroll
            for (int m = 8; m >= 1; m >>= 1) {
                s += __shfl_xor(s, m);
                q += __shfl_xor(q, m);
            }
            if (l15 == 0) {
                int rl = mrow + mt * 16 + lg * 4 + r;
                part_s[w >> 1][rl] = s;
                part_q[w >> 1][rl] = q;
            }
        }
    }
    __syncthreads();

    #pragma unroll
    for (int mt = 0; mt < 2; ++mt) {
        #pragma unroll
        for (int r = 0; r < 4; ++r) {
            int rl = mrow + mt * 16 + lg * 4 + r;
            float s  = part_s[0][rl] + part_s[1][rl];
            float q  = part_q[0][rl] + part_q[1][rl];
            float mu = s * (1.0f / H);
            float rs = rsqrtf(q * (1.0f / H) - mu * mu + LN_EPS);
            #pragma unroll
            for (int nt = 0; nt < 4; ++nt) {
                float v = (acc[mt][nt][r] - mu) * rs * g1c[nt] + be1c[nt];
                v = v / (1.0f + __expf(-v));
                smem[rl * 136 + ncol + nt * 16 + l15] = f2bf(v);
            }
        }
    }
    __syncthreads();

    const ushort* ph0 = smem + (size_t)rA0 * 136;
    const ushort* ph1 = smem + (size_t)rA1 * 136;
    const ushort* pw2 = W2t + (size_t)(ncol + l15) * 128;

    f32x4 acc2[2][4];
    #pragma unroll
    for (int nt = 0; nt < 4; ++nt) {
        float bb = b2[ncol + nt * 16 + l15];
        #pragma unroll
        for (int mt = 0; mt < 2; ++mt)
            acc2[mt][nt] = (f32x4){bb, bb, bb, bb};
    }
    #pragma unroll
    for (int ks = 0; ks < 4; ++ks) {
        int k0 = ks * 32 + lg * 8;
        bf16x8 a0 = *reinterpret_cast<const bf16x8*>(ph0 + k0);
        bf16x8 a1 = *reinterpret_cast<const bf16x8*>(ph1 + k0);
        #pragma unroll
        for (int nt = 0; nt < 4; ++nt) {
            bf16x8 bfr = *reinterpret_cast<const bf16x8*>(pw2 + (size_t)nt * 16 * 128 + k0);
            acc2[0][nt] = mfma16(a0, bfr, acc2[0][nt]);
            acc2[1][nt] = mfma16(a1, bfr, acc2[1][nt]);
        }
    }

    // residual + x_out store; keep o in acc2 for the Pa/Pb phase
    #pragma unroll
    for (int mt = 0; mt < 2; ++mt) {
        #pragma unroll
        for (int r = 0; r < 4; ++r) {
            int row = row0 + mrow + mt * 16 + lg * 4 + r;
            if (row < N) {
                const float* rp = x + (size_t)row * H;
                float* op = x_out + (size_t)row * H;
                #pragma unroll
                for (int nt = 0; nt < 4; ++nt) {
                    int c = ncol + nt * 16 + l15;
                    float o = acc2[mt][nt][r] + rp[c];
                    op[c] = o;
                    acc2[mt][nt][r] = o;
                }
            }
        }
    }
    __syncthreads();            // mm2 h-reads done -> reuse smem for xo

    #pragma unroll
    for (int mt = 0; mt < 2; ++mt) {
        #pragma unroll
        for (int r = 0; r < 4; ++r) {
            int rl = mrow + mt * 16 + lg * 4 + r;
            #pragma unroll
            for (int nt = 0; nt < 4; ++nt)
                smem[rl * 136 + ncol + nt * 16 + l15] = f2bf(acc2[mt][nt][r]);
        }
    }
    __syncthreads();

    const ushort* px0 = smem + (size_t)rA0 * 136 + lg * 8;
    const ushort* px1 = smem + (size_t)rA1 * 136 + lg * 8;
    const ushort* pwa = We1t + (size_t)(ncol + l15) * 384 + lg * 8;
    const ushort* pwb = pwa + 128;

    f32x4 aa[2][4], ab[2][4];
    #pragma unroll
    for (int mt = 0; mt < 2; ++mt)
        #pragma unroll
        for (int nt = 0; nt < 4; ++nt) {
            aa[mt][nt] = (f32x4){0.f, 0.f, 0.f, 0.f};
            ab[mt][nt] = (f32x4){0.f, 0.f, 0.f, 0.f};
        }

    #pragma unroll
    for (int t = 0; t < 4; ++t) {
        bf16x8 a0 = *reinterpret_cast<const bf16x8*>(px0 + t * 32);
        bf16x8 a1 = *reinterpret_cast<const bf16x8*>(px1 + t * 32);
        #pragma unroll
        for (int nt = 0; nt < 4; ++nt) {
            bf16x8 ba = *reinterpret_cast<const bf16x8*>(pwa + (size_t)nt * 16 * 384 + t * 32);
            bf16x8 bb = *reinterpret_cast<const bf16x8*>(pwb + (size_t)nt * 16 * 384 + t * 32);
            aa[0][nt] = mfma16(a0, ba, aa[0][nt]);
            aa[1][nt] = mfma16(a1, ba, aa[1][nt]);
            ab[0][nt] = mfma16(a0, bb, ab[0][nt]);
            ab[1][nt] = mfma16(a1, bb, ab[1][nt]);
        }
    }

    #pragma unroll
    for (int mt = 0; mt < 2; ++mt) {
        #pragma unroll
        for (int r = 0; r < 4; ++r) {
            int row = row0 + mrow + mt * 16 + lg * 4 + r;
            if (row < N) {
                ushort* pa = Pa + (size_t)row * H;
                ushort* pb = Pb + (size_t)row * H;
                #pragma unroll
                for (int nt = 0; nt < 4; ++nt) {
                    int c = ncol + nt * 16 + l15;
                    pa[c] = f2bf(aa[mt][nt][r]);
                    pb[c] = f2bf(ab[mt][nt][r]);
                }
            }
        }
    }
}

// ---------------------------------------------------------------------------
// Edge MLP (R9 structure): h = Pa[s]+Pb[d] + e@W1c + b1 -> LN -> SiLU -> @W2
// -> +e.  EBF=true: e staged/residual from bf16 copy (half the bytes).
// ---------------------------------------------------------------------------
template<bool EBF>
__global__ __launch_bounds__(256, 4) void edge_mlp_kernel(
    const ushort* __restrict__ Pa, const ushort* __restrict__ Pb,
    const float* __restrict__ e, const ushort* __restrict__ ebf,
    const int* __restrict__ ei,
    const ushort* __restrict__ W1t,  // [128][384]; e-part at k offset 256
    const float* __restrict__ b1,
    const float* __restrict__ g1, const float* __restrict__ be1,
    const ushort* __restrict__ W2t, const float* __restrict__ b2,
    float* __restrict__ e_out, int E)
{
    __shared__ ushort es[64 * 136];             // e bf16 (phase1) / h (phase2)
    __shared__ ushort ps[64 * 136];             // Pa[s]+Pb[d] bf16
    __shared__ float part_s[2][64], part_q[2][64];

    const int tid = threadIdx.x;
    const int row0 = blockIdx.x * 64;

    // ---- stage psum rows: ps[r] = Pa[s[r]] + Pb[d[r]] ----
    for (int idx = tid; idx < 64 * 16; idx += 256) {
        int r = idx >> 4, c = idx & 15;
        int rr = min(row0 + r, E - 1);
        int s = ei[rr], d = ei[E + rr];
        bf16x8 va = *reinterpret_cast<const bf16x8*>(Pa + (size_t)s * H + c * 8);
        bf16x8 vb = *reinterpret_cast<const bf16x8*>(Pb + (size_t)d * H + c * 8);
        float f0 = bf2f((ushort)va[0]) + bf2f((ushort)vb[0]);
        float f1 = bf2f((ushort)va[1]) + bf2f((ushort)vb[1]);
        float f2 = bf2f((ushort)va[2]) + bf2f((ushort)vb[2]);
        float f3 = bf2f((ushort)va[3]) + bf2f((ushort)vb[3]);
        float f4 = bf2f((ushort)va[4]) + bf2f((ushort)vb[4]);
        float f5 = bf2f((ushort)va[5]) + bf2f((ushort)vb[5]);
        float f6 = bf2f((ushort)va[6]) + bf2f((ushort)vb[6]);
        float f7 = bf2f((ushort)va[7]) + bf2f((ushort)vb[7]);
        uint4 pk = make_uint4(cvt_pk(f0, f1), cvt_pk(f2, f3),
                              cvt_pk(f4, f5), cvt_pk(f6, f7));
        *reinterpret_cast<uint4*>(&ps[r * 136 + c * 8]) = pk;
    }

    // ---- stage e rows -> bf16 LDS ----
    if constexpr (EBF) {
        for (int idx = tid; idx < 64 * 16; idx += 256) {
            int r = idx >> 4, c = idx & 15;
            int row = row0 + r;
            bf16x8 v = (bf16x8){0,0,0,0,0,0,0,0};
            if (row < E)
                v = *reinterpret_cast<const bf16x8*>(ebf + (size_t)row * H + c * 8);
            *reinterpret_cast<bf16x8*>(&es[r * 136 + c * 8]) = v;
        }
    } else {
        for (int idx = tid; idx < 64 * 32; idx += 256) {
            int r = idx >> 5, c4 = idx & 31;
            int row = row0 + r;
            float4 v = make_float4(0.f, 0.f, 0.f, 0.f);
            if (row < E)
                v = reinterpret_cast<const float4*>(e + (size_t)row * H)[c4];
            uint2 pk = make_uint2(cvt_pk(v.x, v.y), cvt_pk(v.z, v.w));
            *reinterpret_cast<uint2*>(&es[r * 136 + c4 * 4]) = pk;
        }
    }
    __syncthreads();

    const int lane = tid & 63, w = tid >> 6;
    const int l15 = lane & 15, lg = lane >> 4;
    const int mrow = (w & 1) * 32, ncol = (w >> 1) * 64;
    const int rA0 = mrow + l15, rA1 = mrow + 16 + l15;

    const ushort* pe0 = es + (size_t)rA0 * 136 + lg * 8;
    const ushort* pe1 = es + (size_t)rA1 * 136 + lg * 8;
    const ushort* pw1 = W1t + (size_t)(ncol + l15) * 384 + 256 + lg * 8;

    f32x4 acc[2][4];
    #pragma unroll
    for (int mt = 0; mt < 2; ++mt)
        #pragma unroll
        for (int nt = 0; nt < 4; ++nt)
            acc[mt][nt] = (f32x4){0.f, 0.f, 0.f, 0.f};

    // ---- mm1: e @ W1c  (K=128, pure LDS) ----
    #pragma unroll
    for (int t = 0; t < 4; ++t) {
        bf16x8 a0 = *reinterpret_cast<const bf16x8*>(pe0 + t * 32);
        bf16x8 a1 = *reinterpret_cast<const bf16x8*>(pe1 + t * 32);
        #pragma unroll
        for (int nt = 0; nt < 4; ++nt) {
            bf16x8 bfr = *reinterpret_cast<const bf16x8*>(pw1 + (size_t)nt * 16 * 384 + t * 32);
            acc[0][nt] = mfma16(a0, bfr, acc[0][nt]);
            acc[1][nt] = mfma16(a1, bfr, acc[1][nt]);
        }
    }

    // ---- + b1 + psum, LN stats ----
    float b1c[4], g1c[4], be1c[4];
    #pragma unroll
    for (int nt = 0; nt < 4; ++nt) {
        int c = ncol + nt * 16 + l15;
        b1c[nt] = b1[c]; g1c[nt] = g1[c]; be1c[nt] = be1[c];
    }
    #pragma unroll
    for (int mt = 0; mt < 2; ++mt)
        #pragma unroll
        for (int r = 0; r < 4; ++r) {
            int rl = mrow + mt * 16 + lg * 4 + r;
            #pragma unroll
            for (int nt = 0; nt < 4; ++nt)
                acc[mt][nt][r] += b1c[nt] + bf2f(ps[rl * 136 + ncol + nt * 16 + l15]);
        }

    #pragma unroll
    for (int mt = 0; mt < 2; ++mt) {
        #pragma unroll
        for (int r = 0; r < 4; ++r) {
            float s = acc[mt][0][r] + acc[mt][1][r] + acc[mt][2][r] + acc[mt][3][r];
            float q = acc[mt][0][r] * acc[mt][0][r] + acc[mt][1][r] * acc[mt][1][r]
                    + acc[mt][2][r] * acc[mt][2][r] + acc[mt][3][r] * acc[mt][3][r];
            #pragma unroll
            for (int m = 8; m >= 1; m >>= 1) {
                s += __shfl_xor(s, m);
                q += __shfl_xor(q, m);
            }
            if (l15 == 0) {
                int rl = mrow + mt * 16 + lg * 4 + r;
                part_s[w >> 1][rl] = s;
                part_q[w >> 1][rl] = q;
            }
        }
    }
    __syncthreads();   // separates es reads from h-writes too

    // ---- LN + SiLU -> h (aliases es) ----
    #pragma unroll
    for (int mt = 0; mt < 2; ++mt) {
        #pragma unroll
        for (int r = 0; r < 4; ++r) {
            int rl = mrow + mt * 16 + lg * 4 + r;
            float s  = part_s[0][rl] + part_s[1][rl];
            float q  = part_q[0][rl] + part_q[1][rl];
            float mu = s * (1.0f / H);
            float rs = rsqrtf(q * (1.0f / H) - mu * mu + LN_EPS);
            #pragma unroll
            for (int nt = 0; nt < 4; ++nt) {
                float v = (acc[mt][nt][r] - mu) * rs * g1c[nt] + be1c[nt];
                v = v / (1.0f + __expf(-v));
                es[rl * 136 + ncol + nt * 16 + l15] = f2bf(v);
            }
        }
    }
    __syncthreads();

    // ---- mm2 ----
    const ushort* ph0 = es + (size_t)rA0 * 136;
    const ushort* ph1 = es + (size_t)rA1 * 136;
    const ushort* pw2 = W2t + (size_t)(ncol + l15) * 128;

    f32x4 acc2[2][4];
    #pragma unroll
    for (int nt = 0; nt < 4; ++nt) {
        float bb = b2[ncol + nt * 16 + l15];
        #pragma unroll
        for (int mt = 0; mt < 2; ++mt)
            acc2[mt][nt] = (f32x4){bb, bb, bb, bb};
    }
    #pragma unroll
    for (int ks = 0; ks < 4; ++ks) {
        int k0 = ks * 32 + lg * 8;
        bf16x8 a0 = *reinterpret_cast<const bf16x8*>(ph0 + k0);
        bf16x8 a1 = *reinterpret_cast<const bf16x8*>(ph1 + k0);
        #pragma unroll
        for (int nt = 0; nt < 4; ++nt) {
            bf16x8 bfr = *reinterpret_cast<const bf16x8*>(pw2 + (size_t)nt * 16 * 128 + k0);
            acc2[0][nt] = mfma16(a0, bfr, acc2[0][nt]);
            acc2[1][nt] = mfma16(a1, bfr, acc2[1][nt]);
        }
    }

    // ---- residual + store ----
    #pragma unroll
    for (int mt = 0; mt < 2; ++mt) {
        #pragma unroll
        for (int r = 0; r < 4; ++r) {
            int row = row0 + mrow + mt * 16 + lg * 4 + r;
            if (row < E) {
                float* op = e_out + (size_t)row * H;
                #pragma unroll
                for (int nt = 0; nt < 4; ++nt) {
                    int c = ncol + nt * 16 + l15;
                    float res;
                    if constexpr (EBF) res = bf2f(ebf[(size_t)row * H + c]);
                    else               res = e[(size_t)row * H + c];
                    op[c] = acc2[mt][nt][r] + res;
                }
            }
        }
    }
}

// ---------------------------------------------------------------------------
extern "C" void kernel_launch(void* const* d_in, const int* in_sizes, int n_in,
                              void* d_out, int out_size, void* d_ws, size_t ws_size,
                              hipStream_t stream)
{
    const float* x     = (const float*)d_in[0];
    const int*   ei    = (const int*)  d_in[1];
    const float* e     = (const float*)d_in[2];
    const float* Wn1   = (const float*)d_in[3];
    const float* bn1   = (const float*)d_in[4];
    const float* gn1   = (const float*)d_in[5];
    const float* betan1= (const float*)d_in[6];
    const float* Wn2   = (const float*)d_in[7];
    const float* bn2   = (const float*)d_in[8];
    const float* We1   = (const float*)d_in[9];
    const float* be1   = (const float*)d_in[10];
    const float* ge1   = (const float*)d_in[11];
    const float* betae1= (const float*)d_in[12];
    const float* We2   = (const float*)d_in[13];
    const float* be2   = (const float*)d_in[14];

    const int N = in_sizes[0] / H;
    const int E = in_sizes[2] / H;

    float* x_out = (float*)d_out;
    float* e_out = (float*)d_out + (long long)N * H;

    char* p0 = (char*)d_ws;
    char* p = p0;
    float*  msgs = (float*)p;            p += (size_t)N * H * sizeof(float);
    ushort* Pa   = (ushort*)p;           p += (size_t)N * H * sizeof(ushort);
    ushort* Pb   = (ushort*)p;           p += (size_t)N * H * sizeof(ushort);
    ushort* Wn1t = (ushort*)p;           p += (size_t)256 * H * sizeof(ushort);
    ushort* Wn2t = (ushort*)p;           p += (size_t)H * H * sizeof(ushort);
    ushort* We1t = (ushort*)p;           p += (size_t)384 * H * sizeof(ushort);
    ushort* We2t = (ushort*)p;           p += (size_t)H * H * sizeof(ushort);
    p = (char*)(((size_t)p + 15) & ~(size_t)15);
    int* cnt    = (int*)p;               p += (size_t)N * sizeof(int);
    int* off    = (int*)p;               p += ((size_t)N + 1) * sizeof(int);
    int* cursor = (int*)p;               p += (size_t)N * sizeof(int);
    int* sorted = (int*)p;               p += (size_t)E * sizeof(int);
    p = (char*)(((size_t)p + 15) & ~(size_t)15);
    ushort* ebf = (ushort*)p;            p += (size_t)E * H * sizeof(ushort);

    const bool use_ebf = ((size_t)(p - p0) <= ws_size);

    wtrans_kernel<<<(256 * H + 255) / 256, 256, 0, stream>>>(Wn1, Wn1t, 256);
    wtrans_kernel<<<(H * H + 255) / 256, 256, 0, stream>>>(Wn2, Wn2t, H);
    wtrans_kernel<<<(384 * H + 255) / 256, 256, 0, stream>>>(We1, We1t, 384);
    wtrans_kernel<<<(H * H + 255) / 256, 256, 0, stream>>>(We2, We2t, H);

    hipMemsetAsync(cnt, 0, (size_t)N * sizeof(int), stream);
    hist_kernel<<<(E + 255) / 256, 256, 0, stream>>>(ei, cnt, E);
    scan_kernel<<<1, 1024, 0, stream>>>(cnt, off, cursor, N);
    reorder_kernel<<<(E + 255) / 256, 256, 0, stream>>>(ei, cursor, sorted, E);
    segsum_kernel<<<(N + 3) / 4, 256, 0, stream>>>(
        e, sorted, off, msgs, use_ebf ? ebf : nullptr, N);

    {
        int blocks = (N + 63) / 64;
        node_mlp_kernel<<<blocks, 256, 0, stream>>>(
            x, msgs, Wn1t, bn1, gn1, betan1, Wn2t, bn2, We1t,
            x_out, Pa, Pb, N);
    }
    {
        int blocks = (E + 63) / 64;
        if (use_ebf)
            edge_mlp_kernel<true><<<blocks, 256, 0, stream>>>(
                Pa, Pb, e, ebf, ei, We1t, be1, ge1, betae1, We2t, be2, e_out, E);
        else
            edge_mlp_kernel<false><<<blocks, 256, 0, stream>>>(
                Pa, Pb, e, ebf, ei, We1t, be1, ge1, betae1, We2t, be2, e_out, E);
    }
}

// Round 14
// 752.292 us; speedup vs baseline: 1.1142x; 1.1142x over previous
//
#include <hip/hip_runtime.h>

#define H 128
#define LN_EPS 1e-5f

typedef __attribute__((ext_vector_type(8))) short bf16x8;
typedef __attribute__((ext_vector_type(4))) float f32x4;

__device__ __forceinline__ ushort f2bf(float f) {
    unsigned u = __builtin_bit_cast(unsigned, f);
    u += 0x7fffu + ((u >> 16) & 1u);          // RNE
    return (ushort)(u >> 16);
}

__device__ __forceinline__ float bf2f(ushort u) {
    return __builtin_bit_cast(float, (unsigned)u << 16);
}

// 2x fp32 -> packed bf16x2 (RNE), single instruction
__device__ __forceinline__ unsigned cvt_pk(float lo, float hi) {
    unsigned r;
    asm("v_cvt_pk_bf16_f32 %0, %1, %2" : "=v"(r) : "v"(lo), "v"(hi));
    return r;
}

__device__ __forceinline__ f32x4 mfma16(bf16x8 a, bf16x8 b, f32x4 c) {
    return __builtin_amdgcn_mfma_f32_16x16x32_bf16(a, b, c, 0, 0, 0);
}

// ---------------------------------------------------------------------------
// counting-sort by destination, then gather-sum (replaces atomic scatter)
// ---------------------------------------------------------------------------
__global__ __launch_bounds__(256) void hist_kernel(
    const int* __restrict__ ei, int* __restrict__ cnt, int E)
{
    int i = blockIdx.x * 256 + threadIdx.x;
    if (i < E) atomicAdd(&cnt[ei[E + i]], 1);
}

__global__ __launch_bounds__(1024) void scan_kernel(
    const int* __restrict__ cnt, int* __restrict__ off,
    int* __restrict__ cursor, int N)
{
    __shared__ int s[1024];
    const int t = threadIdx.x;
    const int chunk = (N + 1023) / 1024;
    const int lo = t * chunk, hi = min(lo + chunk, N);
    int sum = 0;
    for (int i = lo; i < hi; ++i) sum += cnt[i];
    s[t] = sum;
    __syncthreads();
    for (int d = 1; d < 1024; d <<= 1) {
        int v = (t >= d) ? s[t - d] : 0;
        __syncthreads();
        s[t] += v;
        __syncthreads();
    }
    int running = s[t] - sum;
    for (int i = lo; i < hi; ++i) {
        off[i] = running;
        cursor[i] = running;
        running += cnt[i];
    }
    if (t == 1023) off[N] = running;
}

__global__ __launch_bounds__(256) void reorder_kernel(
    const int* __restrict__ ei, int* __restrict__ cursor,
    int* __restrict__ sorted, int E)
{
    int i = blockIdx.x * 256 + threadIdx.x;
    if (i < E) {
        int pos = atomicAdd(&cursor[ei[E + i]], 1);
        sorted[pos] = i;
    }
}

__global__ __launch_bounds__(256) void segsum_kernel(
    const float* __restrict__ e, const int* __restrict__ sorted,
    const int* __restrict__ off, float* __restrict__ msgs, int N)
{
    int node = blockIdx.x * 4 + (threadIdx.x >> 6);
    int lane = threadIdx.x & 63;
    if (node >= N) return;
    int beg = off[node], end = off[node + 1];
    float ax = 0.f, ay = 0.f;
    for (int base = beg; base < end; base += 64) {
        int eid_l = (base + lane < end) ? sorted[base + lane] : 0;
        int cnt = min(64, end - base);
        int i = 0;
        for (; i + 4 <= cnt; i += 4) {
            int e0 = __shfl(eid_l, i), e1 = __shfl(eid_l, i + 1);
            int e2 = __shfl(eid_l, i + 2), e3 = __shfl(eid_l, i + 3);
            float2 v0 = *reinterpret_cast<const float2*>(e + (size_t)e0 * H + lane * 2);
            float2 v1 = *reinterpret_cast<const float2*>(e + (size_t)e1 * H + lane * 2);
            float2 v2 = *reinterpret_cast<const float2*>(e + (size_t)e2 * H + lane * 2);
            float2 v3 = *reinterpret_cast<const float2*>(e + (size_t)e3 * H + lane * 2);
            ax += v0.x + v1.x + v2.x + v3.x;
            ay += v0.y + v1.y + v2.y + v3.y;
        }
        for (; i < cnt; ++i) {
            int eid = __shfl(eid_l, i);
            float2 v = *reinterpret_cast<const float2*>(e + (size_t)eid * H + lane * 2);
            ax += v.x; ay += v.y;
        }
    }
    *reinterpret_cast<float2*>(msgs + (size_t)node * H + lane * 2) = make_float2(ax, ay);
}

// ---------------------------------------------------------------------------
// Merged weight prep: all 4 W[K][128] fp32 -> Wt[128][K] bf16 in one launch.
// ---------------------------------------------------------------------------
__global__ __launch_bounds__(256) void wtrans4_kernel(
    const float* __restrict__ W0, ushort* __restrict__ T0,   // K=256
    const float* __restrict__ W1, ushort* __restrict__ T1,   // K=128
    const float* __restrict__ W2, ushort* __restrict__ T2,   // K=384
    const float* __restrict__ W3, ushort* __restrict__ T3)   // K=128
{
    int idx = blockIdx.x * 256 + threadIdx.x;
    const int S0 = 256 * H, S1 = S0 + 128 * H, S2 = S1 + 384 * H, S3 = S2 + 128 * H;
    const float* W; ushort* T; int K; int base;
    if      (idx < S0) { W = W0; T = T0; K = 256; base = 0;  }
    else if (idx < S1) { W = W1; T = T1; K = 128; base = S0; }
    else if (idx < S2) { W = W2; T = T2; K = 384; base = S1; }
    else if (idx < S3) { W = W3; T = T3; K = 128; base = S2; }
    else return;
    int j = idx - base;
    int k = j >> 7, n = j & (H - 1);
    T[n * K + k] = f2bf(W[j]);
}

// ---------------------------------------------------------------------------
// Node MLP (fused with Pa/Pb precompute):
//   [x|msgs](256) -> L1 -> LN -> SiLU -> L2 -> +x -> x_out
//   then Pa = xo@We1[0:128], Pb = xo@We1[128:256]
// ---------------------------------------------------------------------------
__global__ __launch_bounds__(256, 3) void node_mlp_kernel(
    const float* __restrict__ x, const float* __restrict__ msgs,
    const ushort* __restrict__ W1t, const float* __restrict__ b1,
    const float* __restrict__ g1, const float* __restrict__ be1,
    const ushort* __restrict__ W2t, const float* __restrict__ b2,
    const ushort* __restrict__ We1t,
    float* __restrict__ x_out,
    ushort* __restrict__ Pa, ushort* __restrict__ Pb, int N)
{
    __shared__ ushort smem[64 * 264];    // staging; h/xo [64][136] alias
    __shared__ float part_s[2][64], part_q[2][64];

    const int tid = threadIdx.x;
    const int row0 = blockIdx.x * 64;

    for (int idx = tid; idx < 64 * 64; idx += 256) {
        int r = idx >> 6, c4 = idx & 63;
        int row = row0 + r;
        float4 v = make_float4(0.f, 0.f, 0.f, 0.f);
        if (row < N)
            v = (c4 < 32) ? reinterpret_cast<const float4*>(x + (size_t)row * H)[c4]
                          : reinterpret_cast<const float4*>(msgs + (size_t)row * H)[c4 - 32];
        uint2 pk = make_uint2(cvt_pk(v.x, v.y), cvt_pk(v.z, v.w));
        *reinterpret_cast<uint2*>(&smem[r * 264 + c4 * 4]) = pk;
    }
    __syncthreads();

    const int lane = tid & 63, w = tid >> 6;
    const int l15 = lane & 15, lg = lane >> 4;
    const int mrow = (w & 1) * 32, ncol = (w >> 1) * 64;
    const int rA0 = mrow + l15, rA1 = mrow + 16 + l15;

    const ushort* pi0 = smem + (size_t)rA0 * 264;
    const ushort* pi1 = smem + (size_t)rA1 * 264;
    const ushort* pw1 = W1t + (size_t)(ncol + l15) * 256;

    f32x4 acc[2][4];
    #pragma unroll
    for (int mt = 0; mt < 2; ++mt)
        #pragma unroll
        for (int nt = 0; nt < 4; ++nt)
            acc[mt][nt] = (f32x4){0.f, 0.f, 0.f, 0.f};

    #pragma unroll
    for (int ks = 0; ks < 8; ++ks) {
        int k0 = ks * 32 + lg * 8;
        bf16x8 a0 = *reinterpret_cast<const bf16x8*>(pi0 + k0);
        bf16x8 a1 = *reinterpret_cast<const bf16x8*>(pi1 + k0);
        #pragma unroll
        for (int nt = 0; nt < 4; ++nt) {
            bf16x8 bfr = *reinterpret_cast<const bf16x8*>(pw1 + (size_t)nt * 16 * 256 + k0);
            acc[0][nt] = mfma16(a0, bfr, acc[0][nt]);
            acc[1][nt] = mfma16(a1, bfr, acc[1][nt]);
        }
    }

    float b1c[4], g1c[4], be1c[4];
    #pragma unroll
    for (int nt = 0; nt < 4; ++nt) {
        int c = ncol + nt * 16 + l15;
        b1c[nt] = b1[c]; g1c[nt] = g1[c]; be1c[nt] = be1[c];
    }
    #pragma unroll
    for (int mt = 0; mt < 2; ++mt)
        #pragma unroll
        for (int nt = 0; nt < 4; ++nt)
            #pragma unroll
            for (int r = 0; r < 4; ++r)
                acc[mt][nt][r] += b1c[nt];

    #pragma unroll
    for (int mt = 0; mt < 2; ++mt) {
        #pragma unroll
        for (int r = 0; r < 4; ++r) {
            float s = acc[mt][0][r] + acc[mt][1][r] + acc[mt][2][r] + acc[mt][3][r];
            float q = acc[mt][0][r] * acc[mt][0][r] + acc[mt][1][r] * acc[mt][1][r]
                    + acc[mt][2][r] * acc[mt][2][r] + acc[mt][3][r] * acc[mt][3][r];
            #pragma unroll
            for (int m = 8; m >= 1; m >>= 1) {
                s += __shfl_xor(s, m);
                q += __shfl_xor(q, m);
            }
            if (l15 == 0) {
                int rl = mrow + mt * 16 + lg * 4 + r;
                part_s[w >> 1][rl] = s;
                part_q[w >> 1][rl] = q;
            }
        }
    }
    __syncthreads();

    #pragma unroll
    for (int mt = 0; mt < 2; ++mt) {
        #pragma unroll
        for (int r = 0; r < 4; ++r) {
            int rl = mrow + mt * 16 + lg * 4 + r;
            float s  = part_s[0][rl] + part_s[1][rl];
            float q  = part_q[0][rl] + part_q[1][rl];
            float mu = s * (1.0f / H);
            float rs = rsqrtf(q * (1.0f / H) - mu * mu + LN_EPS);
            #pragma unroll
            for (int nt = 0; nt < 4; ++nt) {
                float v = (acc[mt][nt][r] - mu) * rs * g1c[nt] + be1c[nt];
                v = v / (1.0f + __expf(-v));
                smem[rl * 136 + ncol + nt * 16 + l15] = f2bf(v);
            }
        }
    }
    __syncthreads();

    const ushort* ph0 = smem + (size_t)rA0 * 136;
    const ushort* ph1 = smem + (size_t)rA1 * 136;
    const ushort* pw2 = W2t + (size_t)(ncol + l15) * 128;

    f32x4 acc2[2][4];
    #pragma unroll
    for (int nt = 0; nt < 4; ++nt) {
        float bb = b2[ncol + nt * 16 + l15];
        #pragma unroll
        for (int mt = 0; mt < 2; ++mt)
            acc2[mt][nt] = (f32x4){bb, bb, bb, bb};
    }
    #pragma unroll
    for (int ks = 0; ks < 4; ++ks) {
        int k0 = ks * 32 + lg * 8;
        bf16x8 a0 = *reinterpret_cast<const bf16x8*>(ph0 + k0);
        bf16x8 a1 = *reinterpret_cast<const bf16x8*>(ph1 + k0);
        #pragma unroll
        for (int nt = 0; nt < 4; ++nt) {
            bf16x8 bfr = *reinterpret_cast<const bf16x8*>(pw2 + (size_t)nt * 16 * 128 + k0);
            acc2[0][nt] = mfma16(a0, bfr, acc2[0][nt]);
            acc2[1][nt] = mfma16(a1, bfr, acc2[1][nt]);
        }
    }

    // residual + x_out store; keep o in acc2 for the Pa/Pb phase
    #pragma unroll
    for (int mt = 0; mt < 2; ++mt) {
        #pragma unroll
        for (int r = 0; r < 4; ++r) {
            int row = row0 + mrow + mt * 16 + lg * 4 + r;
            if (row < N) {
                const float* rp = x + (size_t)row * H;
                float* op = x_out + (size_t)row * H;
                #pragma unroll
                for (int nt = 0; nt < 4; ++nt) {
                    int c = ncol + nt * 16 + l15;
                    float o = acc2[mt][nt][r] + rp[c];
                    op[c] = o;
                    acc2[mt][nt][r] = o;
                }
            }
        }
    }
    __syncthreads();            // mm2 h-reads done -> reuse smem for xo

    #pragma unroll
    for (int mt = 0; mt < 2; ++mt) {
        #pragma unroll
        for (int r = 0; r < 4; ++r) {
            int rl = mrow + mt * 16 + lg * 4 + r;
            #pragma unroll
            for (int nt = 0; nt < 4; ++nt)
                smem[rl * 136 + ncol + nt * 16 + l15] = f2bf(acc2[mt][nt][r]);
        }
    }
    __syncthreads();

    const ushort* px0 = smem + (size_t)rA0 * 136 + lg * 8;
    const ushort* px1 = smem + (size_t)rA1 * 136 + lg * 8;
    const ushort* pwa = We1t + (size_t)(ncol + l15) * 384 + lg * 8;
    const ushort* pwb = pwa + 128;

    f32x4 aa[2][4], ab[2][4];
    #pragma unroll
    for (int mt = 0; mt < 2; ++mt)
        #pragma unroll
        for (int nt = 0; nt < 4; ++nt) {
            aa[mt][nt] = (f32x4){0.f, 0.f, 0.f, 0.f};
            ab[mt][nt] = (f32x4){0.f, 0.f, 0.f, 0.f};
        }

    #pragma unroll
    for (int t = 0; t < 4; ++t) {
        bf16x8 a0 = *reinterpret_cast<const bf16x8*>(px0 + t * 32);
        bf16x8 a1 = *reinterpret_cast<const bf16x8*>(px1 + t * 32);
        #pragma unroll
        for (int nt = 0; nt < 4; ++nt) {
            bf16x8 ba = *reinterpret_cast<const bf16x8*>(pwa + (size_t)nt * 16 * 384 + t * 32);
            bf16x8 bb = *reinterpret_cast<const bf16x8*>(pwb + (size_t)nt * 16 * 384 + t * 32);
            aa[0][nt] = mfma16(a0, ba, aa[0][nt]);
            aa[1][nt] = mfma16(a1, ba, aa[1][nt]);
            ab[0][nt] = mfma16(a0, bb, ab[0][nt]);
            ab[1][nt] = mfma16(a1, bb, ab[1][nt]);
        }
    }

    #pragma unroll
    for (int mt = 0; mt < 2; ++mt) {
        #pragma unroll
        for (int r = 0; r < 4; ++r) {
            int row = row0 + mrow + mt * 16 + lg * 4 + r;
            if (row < N) {
                ushort* pa = Pa + (size_t)row * H;
                ushort* pb = Pb + (size_t)row * H;
                #pragma unroll
                for (int nt = 0; nt < 4; ++nt) {
                    int c = ncol + nt * 16 + l15;
                    pa[c] = f2bf(aa[mt][nt][r]);
                    pb[c] = f2bf(ab[mt][nt][r]);
                }
            }
        }
    }
}

// ---------------------------------------------------------------------------
// Edge MLP (R9 structure, verbatim): h = Pa[s]+Pb[d] + e@W1c + b1 -> LN ->
// SiLU -> @W2 -> +e.  es (e bf16, then h) + ps (psum) staged in LDS.
// ---------------------------------------------------------------------------
__global__ __launch_bounds__(256, 4) void edge_mlp_kernel(
    const ushort* __restrict__ Pa, const ushort* __restrict__ Pb,
    const float* __restrict__ e, const int* __restrict__ ei,
    const ushort* __restrict__ W1t,  // [128][384]; e-part at k offset 256
    const float* __restrict__ b1,
    const float* __restrict__ g1, const float* __restrict__ be1,
    const ushort* __restrict__ W2t, const float* __restrict__ b2,
    float* __restrict__ e_out, int E)
{
    __shared__ ushort es[64 * 136];             // e bf16 (phase1) / h (phase2)
    __shared__ ushort ps[64 * 136];             // Pa[s]+Pb[d] bf16
    __shared__ float part_s[2][64], part_q[2][64];

    const int tid = threadIdx.x;
    const int row0 = blockIdx.x * 64;

    // ---- stage psum rows: ps[r] = Pa[s[r]] + Pb[d[r]] ----
    for (int idx = tid; idx < 64 * 16; idx += 256) {
        int r = idx >> 4, c = idx & 15;
        int rr = min(row0 + r, E - 1);
        int s = ei[rr], d = ei[E + rr];
        bf16x8 va = *reinterpret_cast<const bf16x8*>(Pa + (size_t)s * H + c * 8);
        bf16x8 vb = *reinterpret_cast<const bf16x8*>(Pb + (size_t)d * H + c * 8);
        float f0 = bf2f((ushort)va[0]) + bf2f((ushort)vb[0]);
        float f1 = bf2f((ushort)va[1]) + bf2f((ushort)vb[1]);
        float f2 = bf2f((ushort)va[2]) + bf2f((ushort)vb[2]);
        float f3 = bf2f((ushort)va[3]) + bf2f((ushort)vb[3]);
        float f4 = bf2f((ushort)va[4]) + bf2f((ushort)vb[4]);
        float f5 = bf2f((ushort)va[5]) + bf2f((ushort)vb[5]);
        float f6 = bf2f((ushort)va[6]) + bf2f((ushort)vb[6]);
        float f7 = bf2f((ushort)va[7]) + bf2f((ushort)vb[7]);
        uint4 pk = make_uint4(cvt_pk(f0, f1), cvt_pk(f2, f3),
                              cvt_pk(f4, f5), cvt_pk(f6, f7));
        *reinterpret_cast<uint4*>(&ps[r * 136 + c * 8]) = pk;
    }

    // ---- stage e rows -> bf16 LDS ----
    for (int idx = tid; idx < 64 * 32; idx += 256) {
        int r = idx >> 5, c4 = idx & 31;
        int row = row0 + r;
        float4 v = make_float4(0.f, 0.f, 0.f, 0.f);
        if (row < E)
            v = reinterpret_cast<const float4*>(e + (size_t)row * H)[c4];
        uint2 pk = make_uint2(cvt_pk(v.x, v.y), cvt_pk(v.z, v.w));
        *reinterpret_cast<uint2*>(&es[r * 136 + c4 * 4]) = pk;
    }
    __syncthreads();

    const int lane = tid & 63, w = tid >> 6;
    const int l15 = lane & 15, lg = lane >> 4;
    const int mrow = (w & 1) * 32, ncol = (w >> 1) * 64;
    const int rA0 = mrow + l15, rA1 = mrow + 16 + l15;

    const ushort* pe0 = es + (size_t)rA0 * 136 + lg * 8;
    const ushort* pe1 = es + (size_t)rA1 * 136 + lg * 8;
    const ushort* pw1 = W1t + (size_t)(ncol + l15) * 384 + 256 + lg * 8;

    f32x4 acc[2][4];
    #pragma unroll
    for (int mt = 0; mt < 2; ++mt)
        #pragma unroll
        for (int nt = 0; nt < 4; ++nt)
            acc[mt][nt] = (f32x4){0.f, 0.f, 0.f, 0.f};

    // ---- mm1: e @ W1c  (K=128, pure LDS) ----
    #pragma unroll
    for (int t = 0; t < 4; ++t) {
        bf16x8 a0 = *reinterpret_cast<const bf16x8*>(pe0 + t * 32);
        bf16x8 a1 = *reinterpret_cast<const bf16x8*>(pe1 + t * 32);
        #pragma unroll
        for (int nt = 0; nt < 4; ++nt) {
            bf16x8 bfr = *reinterpret_cast<const bf16x8*>(pw1 + (size_t)nt * 16 * 384 + t * 32);
            acc[0][nt] = mfma16(a0, bfr, acc[0][nt]);
            acc[1][nt] = mfma16(a1, bfr, acc[1][nt]);
        }
    }

    // ---- + b1 + psum, LN stats ----
    float b1c[4], g1c[4], be1c[4];
    #pragma unroll
    for (int nt = 0; nt < 4; ++nt) {
        int c = ncol + nt * 16 + l15;
        b1c[nt] = b1[c]; g1c[nt] = g1[c]; be1c[nt] = be1[c];
    }
    #pragma unroll
    for (int mt = 0; mt < 2; ++mt)
        #pragma unroll
        for (int r = 0; r < 4; ++r) {
            int rl = mrow + mt * 16 + lg * 4 + r;
            #pragma unroll
            for (int nt = 0; nt < 4; ++nt)
                acc[mt][nt][r] += b1c[nt] + bf2f(ps[rl * 136 + ncol + nt * 16 + l15]);
        }

    #pragma unroll
    for (int mt = 0; mt < 2; ++mt) {
        #pragma unroll
        for (int r = 0; r < 4; ++r) {
            float s = acc[mt][0][r] + acc[mt][1][r] + acc[mt][2][r] + acc[mt][3][r];
            float q = acc[mt][0][r] * acc[mt][0][r] + acc[mt][1][r] * acc[mt][1][r]
                    + acc[mt][2][r] * acc[mt][2][r] + acc[mt][3][r] * acc[mt][3][r];
            #pragma unroll
            for (int m = 8; m >= 1; m >>= 1) {
                s += __shfl_xor(s, m);
                q += __shfl_xor(q, m);
            }
            if (l15 == 0) {
                int rl = mrow + mt * 16 + lg * 4 + r;
                part_s[w >> 1][rl] = s;
                part_q[w >> 1][rl] = q;
            }
        }
    }
    __syncthreads();

    // ---- LN + SiLU -> h (aliases es) ----
    #pragma unroll
    for (int mt = 0; mt < 2; ++mt) {
        #pragma unroll
        for (int r = 0; r < 4; ++r) {
            int rl = mrow + mt * 16 + lg * 4 + r;
            float s  = part_s[0][rl] + part_s[1][rl];
            float q  = part_q[0][rl] + part_q[1][rl];
            float mu = s * (1.0f / H);
            float rs = rsqrtf(q * (1.0f / H) - mu * mu + LN_EPS);
            #pragma unroll
            for (int nt = 0; nt < 4; ++nt) {
                float v = (acc[mt][nt][r] - mu) * rs * g1c[nt] + be1c[nt];
                v = v / (1.0f + __expf(-v));
                es[rl * 136 + ncol + nt * 16 + l15] = f2bf(v);
            }
        }
    }
    __syncthreads();

    // ---- mm2 ----
    const ushort* ph0 = es + (size_t)rA0 * 136;
    const ushort* ph1 = es + (size_t)rA1 * 136;
    const ushort* pw2 = W2t + (size_t)(ncol + l15) * 128;

    f32x4 acc2[2][4];
    #pragma unroll
    for (int nt = 0; nt < 4; ++nt) {
        float bb = b2[ncol + nt * 16 + l15];
        #pragma unroll
        for (int mt = 0; mt < 2; ++mt)
            acc2[mt][nt] = (f32x4){bb, bb, bb, bb};
    }
    #pragma unroll
    for (int ks = 0; ks < 4; ++ks) {
        int k0 = ks * 32 + lg * 8;
        bf16x8 a0 = *reinterpret_cast<const bf16x8*>(ph0 + k0);
        bf16x8 a1 = *reinterpret_cast<const bf16x8*>(ph1 + k0);
        #pragma unroll
        for (int nt = 0; nt < 4; ++nt) {
            bf16x8 bfr = *reinterpret_cast<const bf16x8*>(pw2 + (size_t)nt * 16 * 128 + k0);
            acc2[0][nt] = mfma16(a0, bfr, acc2[0][nt]);
            acc2[1][nt] = mfma16(a1, bfr, acc2[1][nt]);
        }
    }

    // ---- residual + store ----
    #pragma unroll
    for (int mt = 0; mt < 2; ++mt) {
        #pragma unroll
        for (int r = 0; r < 4; ++r) {
            int row = row0 + mrow + mt * 16 + lg * 4 + r;
            if (row < E) {
                const float* rp = e + (size_t)row * H;
                float* op = e_out + (size_t)row * H;
                #pragma unroll
                for (int nt = 0; nt < 4; ++nt) {
                    int c = ncol + nt * 16 + l15;
                    op[c] = acc2[mt][nt][r] + rp[c];
                }
            }
        }
    }
}

// ---------------------------------------------------------------------------
extern "C" void kernel_launch(void* const* d_in, const int* in_sizes, int n_in,
                              void* d_out, int out_size, void* d_ws, size_t ws_size,
                              hipStream_t stream)
{
    const float* x     = (const float*)d_in[0];
    const int*   ei    = (const int*)  d_in[1];
    const float* e     = (const float*)d_in[2];
    const float* Wn1   = (const float*)d_in[3];
    const float* bn1   = (const float*)d_in[4];
    const float* gn1   = (const float*)d_in[5];
    const float* betan1= (const float*)d_in[6];
    const float* Wn2   = (const float*)d_in[7];
    const float* bn2   = (const float*)d_in[8];
    const float* We1   = (const float*)d_in[9];
    const float* be1   = (const float*)d_in[10];
    const float* ge1   = (const float*)d_in[11];
    const float* betae1= (const float*)d_in[12];
    const float* We2   = (const float*)d_in[13];
    const float* be2   = (const float*)d_in[14];

    const int N = in_sizes[0] / H;
    const int E = in_sizes[2] / H;

    float* x_out = (float*)d_out;
    float* e_out = (float*)d_out + (long long)N * H;

    char* p = (char*)d_ws;
    float*  msgs = (float*)p;            p += (size_t)N * H * sizeof(float);
    ushort* Pa   = (ushort*)p;           p += (size_t)N * H * sizeof(ushort);
    ushort* Pb   = (ushort*)p;           p += (size_t)N * H * sizeof(ushort);
    ushort* Wn1t = (ushort*)p;           p += (size_t)256 * H * sizeof(ushort);
    ushort* Wn2t = (ushort*)p;           p += (size_t)H * H * sizeof(ushort);
    ushort* We1t = (ushort*)p;           p += (size_t)384 * H * sizeof(ushort);
    ushort* We2t = (ushort*)p;           p += (size_t)H * H * sizeof(ushort);
    p = (char*)(((size_t)p + 15) & ~(size_t)15);
    int* cnt    = (int*)p;               p += (size_t)N * sizeof(int);
    int* off    = (int*)p;               p += ((size_t)N + 1) * sizeof(int);
    int* cursor = (int*)p;               p += (size_t)N * sizeof(int);
    int* sorted = (int*)p;               p += (size_t)E * sizeof(int);

    {
        int total = 256 * H + 128 * H + 384 * H + 128 * H;
        wtrans4_kernel<<<(total + 255) / 256, 256, 0, stream>>>(
            Wn1, Wn1t, Wn2, Wn2t, We1, We1t, We2, We2t);
    }

    hipMemsetAsync(cnt, 0, (size_t)N * sizeof(int), stream);
    hist_kernel<<<(E + 255) / 256, 256, 0, stream>>>(ei, cnt, E);
    scan_kernel<<<1, 1024, 0, stream>>>(cnt, off, cursor, N);
    reorder_kernel<<<(E + 255) / 256, 256, 0, stream>>>(ei, cursor, sorted, E);
    segsum_kernel<<<(N + 3) / 4, 256, 0, stream>>>(e, sorted, off, msgs, N);

    {
        int blocks = (N + 63) / 64;
        node_mlp_kernel<<<blocks, 256, 0, stream>>>(
            x, msgs, Wn1t, bn1, gn1, betan1, Wn2t, bn2, We1t,
            x_out, Pa, Pb, N);
    }
    {
        int blocks = (E + 63) / 64;
        edge_mlp_kernel<<<blocks, 256, 0, stream>>>(
            Pa, Pb, e, ei, We1t, be1, ge1, betae1, We2t, be2, e_out, E);
    }
}